// Round 2
// baseline (13944.749 us; speedup 1.0000x reference)
//
#include <hip/hip_runtime.h>
#include <hip/hip_bf16.h>
#include <stdint.h>

#define TT 1024
#define BB 512
#define II 128
#define HH 256
#define GG 1024
#define NKC 12      // K = 384 = 12 chunks of 32  (x:0..127, h:128..383)
#define GSTR 1026   // gates LDS row stride in dwords (bank-spread)

typedef __attribute__((ext_vector_type(8))) short bf16x8;
typedef __attribute__((ext_vector_type(4))) float f32x4;

__device__ __forceinline__ float fsig(float x)  { return 1.0f / (1.0f + __expf(-x)); }
__device__ __forceinline__ float ftanh(float x) { return 1.0f - 2.0f / (__expf(2.0f * x) + 1.0f); }
__device__ __forceinline__ uint16_t f2bf(float f) {
    return __bfloat16_as_ushort(__float2bfloat16(f));
}

// Pre-swizzle [W_ih(x-part) | W_hh] into MFMA B-fragment order:
// Wswz[kc][ntile][lane][j] = W[k = kc*32 + (lane>>4)*8 + j][col = ntile*16 + (lane&15)]
__global__ __launch_bounds__(256) void prep_kernel(
    const float* __restrict__ W_ih, const float* __restrict__ W_hh,
    uint16_t* __restrict__ Wswz)
{
    int e = blockIdx.x * 256 + threadIdx.x;
    if (e >= NKC * 64 * 64 * 8) return;
    int j = e & 7, lane = (e >> 3) & 63, nt = (e >> 9) & 63, kc = e >> 15;
    int k = kc * 32 + (lane >> 4) * 8 + j;
    int col = nt * 16 + (lane & 15);
    float w = (k < II) ? W_ih[col * (II + 1) + k] : W_hh[col * HH + (k - II)];
    Wswz[e] = f2bf(w);
}

__global__ __launch_bounds__(512) void lstm_kernel(
    const float* __restrict__ x,      // [T][B][I]
    const float* __restrict__ h0, const float* __restrict__ c0,
    const float* __restrict__ z0,
    const uint16_t* __restrict__ Wswz,
    const float* __restrict__ b_ih, const float* __restrict__ b_hh,
    const float* __restrict__ W_ih,   // for the z column (col 128)
    const float* __restrict__ Wfc, const float* __restrict__ bfc,
    float* __restrict__ out)          // [T*B] ++ [B*H] ++ [B*H]
{
    __shared__ __align__(16) uint16_t a_sh[NKC * 4 * 16 * 8]; // [kc][g][row][j] bf16
    __shared__ float g_sh[16 * GSTR];                          // gates [row][col]
    __shared__ float zbuf[16];
    __shared__ float zred[4][2][4];

    const int tid  = threadIdx.x;
    const int lane = tid & 63, w = tid >> 6;
    const int b0   = blockIdx.x * 16;

    // activation role: u-pair + row-quad
    const int up = tid & 127, rq = tid >> 7;
    const int u0 = up * 2;
    // x-stage role
    const int xr = tid >> 5, xc = (tid & 31) * 4;

    // loop-invariant preloads
    float2 bia[4], wz[4];
    #pragma unroll
    for (int g = 0; g < 4; ++g) {
        int c = g * 256 + u0;
        bia[g] = make_float2(b_ih[c] + b_hh[c], b_ih[c + 1] + b_hh[c + 1]);
        wz[g]  = make_float2(W_ih[c * (II + 1) + II], W_ih[(c + 1) * (II + 1) + II]);
    }
    const float2 wfc2 = make_float2(Wfc[u0], Wfc[u0 + 1]);
    const float bfcs = bfc[0];

    // persistent cell state in regs
    float creg[4][2];
    #pragma unroll
    for (int r = 0; r < 4; ++r) {
        int row = rq * 4 + r;
        creg[r][0] = c0[(b0 + row) * HH + u0];
        creg[r][1] = c0[(b0 + row) * HH + u0 + 1];
    }
    // h0 -> A fragments (k = 128+u)
    #pragma unroll
    for (int r = 0; r < 4; ++r) {
        int row = rq * 4 + r;
        int k = II + u0, kc = k >> 5, g = (k >> 3) & 3, j = k & 7;
        uint32_t p = (uint32_t)f2bf(h0[(b0 + row) * HH + u0])
                   | ((uint32_t)f2bf(h0[(b0 + row) * HH + u0 + 1]) << 16);
        *(uint32_t*)&a_sh[((kc * 4 + g) * 16 + row) * 8 + j] = p;
    }
    // x_0 -> A fragments
    {
        float4 xv = *(const float4*)&x[(size_t)(b0 + xr) * II + xc];
        int kc = xc >> 5, g = (xc >> 3) & 3, j = xc & 7;
        ushort4 p;
        p.x = f2bf(xv.x); p.y = f2bf(xv.y); p.z = f2bf(xv.z); p.w = f2bf(xv.w);
        *(ushort4*)&a_sh[((kc * 4 + g) * 16 + xr) * 8 + j] = p;
    }
    if (tid < 16) zbuf[tid] = z0[b0 + tid];

    for (int t = 0; t < TT; ++t) {
        __syncthreads();  // A: a_sh (x_t, h_{t-1}) and zbuf (z_{t-1}) visible

        // prefetch x_{t+1}
        float4 xn = make_float4(0.f, 0.f, 0.f, 0.f);
        if (t + 1 < TT)
            xn = *(const float4*)&x[(size_t)(t + 1) * (BB * II) + (b0 + xr) * II + xc];

        // ---- MFMA phase: gates[16][1024] = A[16][384] * W ----
        f32x4 acc[8];
        #pragma unroll
        for (int nt = 0; nt < 8; ++nt) acc[nt] = (f32x4){0.f, 0.f, 0.f, 0.f};
        #pragma unroll 3
        for (int kc = 0; kc < NKC; ++kc) {
            bf16x8 a = *(const bf16x8*)&a_sh[((kc * 4 + (lane >> 4)) * 16 + (lane & 15)) * 8];
            #pragma unroll
            for (int nt = 0; nt < 8; ++nt) {
                bf16x8 b = *(const bf16x8*)&Wswz[(((size_t)kc * 64 + w * 8 + nt) * 64 + lane) * 8];
                acc[nt] = __builtin_amdgcn_mfma_f32_16x16x32_bf16(a, b, acc[nt], 0, 0, 0);
            }
        }
        // gates -> LDS (D layout: col = lane&15, row = (lane>>4)*4 + i)
        {
            int r0 = (lane >> 4) * 4, cb = w * 128 + (lane & 15);
            #pragma unroll
            for (int nt = 0; nt < 8; ++nt)
                #pragma unroll
                for (int i = 0; i < 4; ++i)
                    g_sh[(r0 + i) * GSTR + cb + nt * 16] = acc[nt][i];
        }
        __syncthreads();  // B: gates ready; all A reads done

        // stage x_{t+1} into A fragments
        {
            int kc = xc >> 5, g = (xc >> 3) & 3, j = xc & 7;
            ushort4 p;
            p.x = f2bf(xn.x); p.y = f2bf(xn.y); p.z = f2bf(xn.z); p.w = f2bf(xn.w);
            *(ushort4*)&a_sh[((kc * 4 + g) * 16 + xr) * 8 + j] = p;
        }

        // ---- activation phase: thread owns 4 rows x 2 units ----
        float pz[4];
        #pragma unroll
        for (int r = 0; r < 4; ++r) {
            int row = rq * 4 + r;
            float zp = zbuf[row];
            float2 G[4];
            #pragma unroll
            for (int g = 0; g < 4; ++g)
                G[g] = *(float2*)&g_sh[row * GSTR + g * 256 + u0];

            float i0 = fsig (G[0].x + bia[0].x + wz[0].x * zp);
            float f0 = fsig (G[1].x + bia[1].x + wz[1].x * zp);
            float g0 = ftanh(G[2].x + bia[2].x + wz[2].x * zp);
            float o0 = fsig (G[3].x + bia[3].x + wz[3].x * zp);
            float i1 = fsig (G[0].y + bia[0].y + wz[0].y * zp);
            float f1 = fsig (G[1].y + bia[1].y + wz[1].y * zp);
            float g1 = ftanh(G[2].y + bia[2].y + wz[2].y * zp);
            float o1 = fsig (G[3].y + bia[3].y + wz[3].y * zp);

            float c0n = f0 * creg[r][0] + i0 * g0;
            float c1n = f1 * creg[r][1] + i1 * g1;
            float h0n = o0 * ftanh(c0n);
            float h1n = o1 * ftanh(c1n);
            creg[r][0] = c0n; creg[r][1] = c1n;

            // h -> A fragments (k = 128+u)
            int k = II + u0, kc = k >> 5, g = (k >> 3) & 3, j = k & 7;
            uint32_t p = (uint32_t)f2bf(h0n) | ((uint32_t)f2bf(h1n) << 16);
            *(uint32_t*)&a_sh[((kc * 4 + g) * 16 + row) * 8 + j] = p;

            pz[r] = h0n * wfc2.x + h1n * wfc2.y;

            if (t == TT - 1) {
                size_t ho = (size_t)TT * BB + (size_t)(b0 + row) * HH + u0;
                out[ho] = h0n; out[ho + 1] = h1n;
                out[ho + (size_t)BB * HH] = c0n; out[ho + (size_t)BB * HH + 1] = c1n;
            }
        }
        // z-partial reduce within wave (wave covers 64 u-pairs of one row-quad half)
        #pragma unroll
        for (int off = 32; off >= 1; off >>= 1) {
            #pragma unroll
            for (int r = 0; r < 4; ++r) pz[r] += __shfl_down(pz[r], off, 64);
        }
        if (lane == 0) {
            #pragma unroll
            for (int r = 0; r < 4; ++r) zred[w >> 1][w & 1][r] = pz[r];
        }
        __syncthreads();  // C: zred + a_sh(h,x) complete

        if (tid < 16) {
            float s = zred[tid >> 2][0][tid & 3] + zred[tid >> 2][1][tid & 3];
            float zt = ftanh(s + bfcs);
            zbuf[tid] = zt;
            out[(size_t)t * BB + b0 + tid] = zt;
        }
    }
}

extern "C" void kernel_launch(void* const* d_in, const int* in_sizes, int n_in,
                              void* d_out, int out_size, void* d_ws, size_t ws_size,
                              hipStream_t stream) {
    const float* x    = (const float*)d_in[0];
    const float* h0   = (const float*)d_in[1];
    const float* c0   = (const float*)d_in[2];
    const float* z0   = (const float*)d_in[3];
    const float* W_ih = (const float*)d_in[4];
    const float* W_hh = (const float*)d_in[5];
    const float* b_ih = (const float*)d_in[6];
    const float* b_hh = (const float*)d_in[7];
    const float* Wfc  = (const float*)d_in[8];
    const float* bfc  = (const float*)d_in[9];
    float* out = (float*)d_out;

    uint16_t* Wswz = (uint16_t*)d_ws;  // 786,432 B

    int prep_total = NKC * 64 * 64 * 8;
    prep_kernel<<<(prep_total + 255) / 256, 256, 0, stream>>>(W_ih, W_hh, Wswz);
    lstm_kernel<<<BB / 16, 512, 0, stream>>>(x, h0, c0, z0, Wswz, b_ih, b_hh, W_ih,
                                             Wfc, bfc, out);
}

// Round 4
// 7662.700 us; speedup vs baseline: 1.8198x; 1.8198x over previous
//
#include <hip/hip_runtime.h>
#include <hip/hip_bf16.h>
#include <stdint.h>

#define TT 1024
#define BB 512
#define II 128
#define HH 256
#define NKC 12          // K = 384 = 12 chunks of 32 (x:0..127, h:128..383)
#define GSTR 132        // gates LDS row stride (floats): 2-way bank alias = free

#define OFF_HBUF 4096   // ws: flags [0,1024), hbuf [4096, 4096+524288) -> 528 KB total

typedef __attribute__((ext_vector_type(8))) short bf16x8;
typedef __attribute__((ext_vector_type(4))) float f32x4;

__device__ __forceinline__ float fsig(float x)  { return 1.0f / (1.0f + __expf(-x)); }
__device__ __forceinline__ float ftanh(float x) { return 1.0f - 2.0f / (__expf(2.0f * x) + 1.0f); }
__device__ __forceinline__ uint16_t f2bf(float f) {
    return __bfloat16_as_ushort(__float2bfloat16(f));
}
__device__ __forceinline__ float bf2lo(uint32_t w) { return __uint_as_float(w << 16); }
__device__ __forceinline__ float bf2hi(uint32_t w) { return __uint_as_float(w & 0xffff0000u); }

// Spin until *f >= v (relaxed agent loads reach the coherence point; clobber
// stops the compiler hoisting the subsequent gather loads above the loop).
__device__ __forceinline__ void spin_ge(uint32_t* f, uint32_t v) {
    uint32_t it = 0;
    while (__hip_atomic_load(f, __ATOMIC_RELAXED, __HIP_MEMORY_SCOPE_AGENT) < v) {
        __builtin_amdgcn_s_sleep(1);
        if (++it > (1u << 27)) break;  // hang-safety: wrong output beats deadlock
    }
    asm volatile("" ::: "memory");
}

__global__ void zero_flags(uint32_t* __restrict__ flags) {
    __hip_atomic_store(&flags[threadIdx.x], 0u, __ATOMIC_RELAXED, __HIP_MEMORY_SCOPE_AGENT);
}

// 256 blocks = 32 groups x 8 roles. Group owns 16 batch rows; role owns 32 h-units
// (its 128 gate cols i/f/g/o). Weights for the slice live in LDS for the whole run.
// h is exchanged between the 8 role-blocks of a group via IF-coherent (sc1) stores,
// gated by per-role monotonic flags (release-stored).
__global__ __launch_bounds__(512, 1) void lstm_kernel(
    const float* __restrict__ x,
    const float* __restrict__ h0, const float* __restrict__ c0,
    const float* __restrict__ z0,
    const float* __restrict__ W_ih, const float* __restrict__ W_hh,
    const float* __restrict__ b_ih, const float* __restrict__ b_hh,
    const float* __restrict__ Wfc, const float* __restrict__ bfc,
    uint32_t* __restrict__ flags, uint32_t* __restrict__ hbuf,
    float* __restrict__ out)
{
    __shared__ __align__(16) uint16_t w_sh[NKC * 8 * 64 * 8];  // 96 KB weight slice
    __shared__ __align__(16) uint16_t a_sh[NKC * 4 * 16 * 8];  // 12 KB A-fragments
    __shared__ float g_sh[16 * GSTR];                          // 8448 B gates
    __shared__ float zp_sh[8 * 16];                            // z partials [role][row]

    const int tid  = threadIdx.x;
    const int lane = tid & 63, wv = tid >> 6;
    const int grp  = blockIdx.x >> 3, role = blockIdx.x & 7;
    const int b0   = grp * 16;
    const int arow = tid >> 5, auu = tid & 31;     // activation: 1 cell/thread
    const int u_g  = role * 32 + auu;
    const int xc   = (tid & 31) * 4;               // x-stage role
    const int grole = wv, grow = (tid >> 2) & 15, gwq = tid & 3;  // gather role

    // ---- one-time: swizzle this block's weight slice straight into LDS ----
    // w_sh[((kc*8+nt)*64+lane)*8+j] = W[k][col], k = kc*32+(lane>>4)*8+j,
    // lc = nt*16+(lane&15), col = (lc>>5)*256 + role*32 + (lc&31)
    #pragma unroll
    for (int i = 0; i < 12; ++i) {
        int eo = i * 512 + tid;
        int lane2 = eo & 63, knt = eo >> 6;
        int nt = knt & 7;
        int k0 = (knt >> 3) * 32 + (lane2 >> 4) * 8;
        int lc = nt * 16 + (lane2 & 15);
        int col = (lc >> 5) * 256 + role * 32 + (lc & 31);
        const float* src = (k0 < II) ? &W_ih[(size_t)col * (II + 1) + k0]
                                     : &W_hh[(size_t)col * HH + (k0 - II)];
        ushort4 lo, hi;
        lo.x = f2bf(src[0]); lo.y = f2bf(src[1]); lo.z = f2bf(src[2]); lo.w = f2bf(src[3]);
        hi.x = f2bf(src[4]); hi.y = f2bf(src[5]); hi.z = f2bf(src[6]); hi.w = f2bf(src[7]);
        *(ushort4*)&w_sh[eo * 8 + 0] = lo;
        *(ushort4*)&w_sh[eo * 8 + 4] = hi;
    }

    // ---- per-thread loop invariants ----
    float bia[4], wzv[4];
    #pragma unroll
    for (int g = 0; g < 4; ++g) {
        int c = g * 256 + u_g;
        bia[g] = b_ih[c] + b_hh[c];
        wzv[g] = W_ih[(size_t)c * (II + 1) + II];   // z column (col 128)
    }
    float wfc8[8];
    #pragma unroll
    for (int j = 0; j < 8; ++j) wfc8[j] = Wfc[grole * 32 + gwq * 8 + j];
    const float bfcs = bfc[0];
    const float z0r  = z0[b0 + arow];
    float c_r = c0[(size_t)(b0 + arow) * HH + u_g];

    // ---- h0 -> a_sh (all roles), x0 -> a_sh ----
    {
        const float* hp = h0 + (size_t)(b0 + grow) * HH + grole * 32 + gwq * 8;
        uint4 pw;
        pw.x = (uint32_t)f2bf(hp[0]) | ((uint32_t)f2bf(hp[1]) << 16);
        pw.y = (uint32_t)f2bf(hp[2]) | ((uint32_t)f2bf(hp[3]) << 16);
        pw.z = (uint32_t)f2bf(hp[4]) | ((uint32_t)f2bf(hp[5]) << 16);
        pw.w = (uint32_t)f2bf(hp[6]) | ((uint32_t)f2bf(hp[7]) << 16);
        *(uint4*)&a_sh[(((4 + grole) * 4 + gwq) * 16 + grow) * 8] = pw;
    }
    {
        float4 xv = *(const float4*)&x[(size_t)(b0 + arow) * II + xc];
        int kcx = xc >> 5, gx = (xc >> 3) & 3, jx = xc & 7;
        ushort4 p;
        p.x = f2bf(xv.x); p.y = f2bf(xv.y); p.z = f2bf(xv.z); p.w = f2bf(xv.w);
        *(ushort4*)&a_sh[((kcx * 4 + gx) * 16 + arow) * 8 + jx] = p;
    }

    for (int t = 0; t <= TT; ++t) {
        // prefetch x_{t+1} (issued before the spin; consumed after barrier B)
        float4 xn = make_float4(0.f, 0.f, 0.f, 0.f);
        if (t + 1 < TT)
            xn = *(const float4*)&x[(size_t)(t + 1) * (BB * II) + (size_t)(b0 + arow) * II + xc];

        if (t > 0) {
            spin_ge(&flags[grp * 8 + grole], (uint32_t)t);
            const int par = (t - 1) & 1;
            uint32_t* hb = hbuf + (((size_t)par * 32 + grp) * 8 + grole) * 256
                         + grow * 16 + gwq * 4;
            uint32_t w0 = __hip_atomic_load(hb + 0, __ATOMIC_RELAXED, __HIP_MEMORY_SCOPE_AGENT);
            uint32_t w1 = __hip_atomic_load(hb + 1, __ATOMIC_RELAXED, __HIP_MEMORY_SCOPE_AGENT);
            uint32_t w2 = __hip_atomic_load(hb + 2, __ATOMIC_RELAXED, __HIP_MEMORY_SCOPE_AGENT);
            uint32_t w3 = __hip_atomic_load(hb + 3, __ATOMIC_RELAXED, __HIP_MEMORY_SCOPE_AGENT);
            uint4 pw; pw.x = w0; pw.y = w1; pw.z = w2; pw.w = w3;
            *(uint4*)&a_sh[(((4 + grole) * 4 + gwq) * 16 + grow) * 8] = pw;
            // z partial: this lane's 8 units dotted with Wfc
            float p = bf2lo(w0) * wfc8[0] + bf2hi(w0) * wfc8[1]
                    + bf2lo(w1) * wfc8[2] + bf2hi(w1) * wfc8[3]
                    + bf2lo(w2) * wfc8[4] + bf2hi(w2) * wfc8[5]
                    + bf2lo(w3) * wfc8[6] + bf2hi(w3) * wfc8[7];
            p += __shfl_xor(p, 1, 64);
            p += __shfl_xor(p, 2, 64);
            if (gwq == 0) zp_sh[grole * 16 + grow] = p;
        }
        __syncthreads();  // A: a_sh (x_t, h_{t-1}) + zp_sh ready

        if (t == TT) {    // epilogue: emit z_{TT-1} only
            if (role == 0 && tid < 16) {
                float s = bfcs;
                #pragma unroll
                for (int r = 0; r < 8; ++r) s += zp_sh[r * 16 + tid];
                out[(size_t)(TT - 1) * BB + b0 + tid] = ftanh(s);
            }
            break;
        }

        // ---- MFMA: gates[16][128] = A[16][384] * Wslice, wave = n-tile ----
        f32x4 acc0 = {0.f, 0.f, 0.f, 0.f}, acc1 = {0.f, 0.f, 0.f, 0.f};
        #pragma unroll
        for (int kc = 0; kc < NKC; kc += 2) {
            bf16x8 a0 = *(const bf16x8*)&a_sh[((kc * 4 + (lane >> 4)) * 16 + (lane & 15)) * 8];
            bf16x8 bv0 = *(const bf16x8*)&w_sh[((kc * 8 + wv) * 64 + lane) * 8];
            acc0 = __builtin_amdgcn_mfma_f32_16x16x32_bf16(a0, bv0, acc0, 0, 0, 0);
            bf16x8 a1 = *(const bf16x8*)&a_sh[(((kc + 1) * 4 + (lane >> 4)) * 16 + (lane & 15)) * 8];
            bf16x8 bv1 = *(const bf16x8*)&w_sh[(((kc + 1) * 8 + wv) * 64 + lane) * 8];
            acc1 = __builtin_amdgcn_mfma_f32_16x16x32_bf16(a1, bv1, acc1, 0, 0, 0);
        }
        f32x4 acc = acc0 + acc1;
        {
            int r0 = (lane >> 4) * 4, cb = wv * 16 + (lane & 15);
            #pragma unroll
            for (int i = 0; i < 4; ++i) g_sh[(r0 + i) * GSTR + cb] = acc[i];
        }
        __syncthreads();  // B: gates ready; all a_sh reads done

        // stage x_{t+1}
        {
            int kcx = xc >> 5, gx = (xc >> 3) & 3, jx = xc & 7;
            ushort4 p;
            p.x = f2bf(xn.x); p.y = f2bf(xn.y); p.z = f2bf(xn.z); p.w = f2bf(xn.w);
            *(ushort4*)&a_sh[((kcx * 4 + gx) * 16 + arow) * 8 + jx] = p;
        }

        // ---- activation: one cell per thread ----
        float zp_;
        if (t == 0) {
            zp_ = z0r;
        } else {
            float s = bfcs;
            #pragma unroll
            for (int r = 0; r < 8; ++r) s += zp_sh[r * 16 + arow];
            zp_ = ftanh(s);
            if (role == 0 && auu == 0)
                out[(size_t)(t - 1) * BB + b0 + arow] = zp_;
        }
        float gi = g_sh[arow * GSTR +      auu] + bia[0] + wzv[0] * zp_;
        float gf = g_sh[arow * GSTR + 32 + auu] + bia[1] + wzv[1] * zp_;
        float gg = g_sh[arow * GSTR + 64 + auu] + bia[2] + wzv[2] * zp_;
        float go = g_sh[arow * GSTR + 96 + auu] + bia[3] + wzv[3] * zp_;
        float ig = fsig(gi), fg = fsig(gf), gc = ftanh(gg), og = fsig(go);
        float cn = fg * c_r + ig * gc;
        c_r = cn;
        float hn = og * ftanh(cn);

        // publish h (bf16 pairs) to the exchange buffer (IF-coherent)
        uint32_t hb16 = f2bf(hn);
        uint32_t nb = __shfl_down(hb16, 1, 64);
        if (!(auu & 1)) {
            __hip_atomic_store(
                hbuf + (((size_t)(t & 1) * 32 + grp) * 8 + role) * 256 + arow * 16 + (auu >> 1),
                hb16 | (nb << 16), __ATOMIC_RELAXED, __HIP_MEMORY_SCOPE_AGENT);
        }

        if (t == TT - 1) {
            size_t ho = (size_t)TT * BB + (size_t)(b0 + arow) * HH + u_g;
            out[ho] = hn;
            out[ho + (size_t)BB * HH] = cn;
        }
        __syncthreads();  // C: every wave's publishes drained (per-wave vmcnt)
        if (tid == 0)
            __hip_atomic_store(&flags[grp * 8 + role], (uint32_t)(t + 1),
                               __ATOMIC_RELEASE, __HIP_MEMORY_SCOPE_AGENT);
    }
}

extern "C" void kernel_launch(void* const* d_in, const int* in_sizes, int n_in,
                              void* d_out, int out_size, void* d_ws, size_t ws_size,
                              hipStream_t stream) {
    const float* x    = (const float*)d_in[0];
    const float* h0   = (const float*)d_in[1];
    const float* c0   = (const float*)d_in[2];
    const float* z0   = (const float*)d_in[3];
    const float* W_ih = (const float*)d_in[4];
    const float* W_hh = (const float*)d_in[5];
    const float* b_ih = (const float*)d_in[6];
    const float* b_hh = (const float*)d_in[7];
    const float* Wfc  = (const float*)d_in[8];
    const float* bfc  = (const float*)d_in[9];
    float* out = (float*)d_out;

    uint32_t* flags = (uint32_t*)d_ws;
    uint32_t* hbuf  = (uint32_t*)((char*)d_ws + OFF_HBUF);

    zero_flags<<<1, 256, 0, stream>>>(flags);
    lstm_kernel<<<256, 512, 0, stream>>>(x, h0, c0, z0, W_ih, W_hh, b_ih, b_hh,
                                         Wfc, bfc, flags, hbuf, out);
}

// Round 5
// 2378.099 us; speedup vs baseline: 5.8638x; 3.2222x over previous
//
#include <hip/hip_runtime.h>
#include <hip/hip_bf16.h>
#include <stdint.h>

#define TT 1024
#define BB 512
#define II 128
#define HH 256
#define NKC 12          // K = 384 = 12 chunks of 32 (x:0..127, h:128..383)
#define GSTR 132        // gates LDS row stride (floats): 2-way bank alias = free

typedef __attribute__((ext_vector_type(8))) short bf16x8;
typedef __attribute__((ext_vector_type(4))) float f32x4;
typedef unsigned long long ull;

__device__ __forceinline__ float fsig(float x)  { return 1.0f / (1.0f + __expf(-x)); }
__device__ __forceinline__ float ftanh(float x) { return 1.0f - 2.0f / (__expf(2.0f * x) + 1.0f); }
__device__ __forceinline__ uint16_t f2bf(float f) {
    return __bfloat16_as_ushort(__float2bfloat16(f));
}
__device__ __forceinline__ float bf2lo(uint32_t w) { return __uint_as_float(w << 16); }
__device__ __forceinline__ float bf2hi(uint32_t w) { return __uint_as_float(w & 0xffff0000u); }

__device__ __forceinline__ void spin_ge(uint32_t* f, uint32_t v) {
    uint32_t it = 0;
    while (__hip_atomic_load(f, __ATOMIC_RELAXED, __HIP_MEMORY_SCOPE_AGENT) < v) {
        __builtin_amdgcn_s_sleep(1);
        if (++it > (1u << 22)) break;  // hang-safety: wrong output beats deadlock
    }
    asm volatile("" ::: "memory");
}

__global__ void zero_flags(uint32_t* __restrict__ flags) {
    __hip_atomic_store(&flags[threadIdx.x], 0u, __ATOMIC_RELAXED, __HIP_MEMORY_SCOPE_AGENT);
}

// ============================================================================
// PRIMARY: stamp-carrying 8B exchange words, no flags, 2 barriers/step.
// 256 blocks = 32 groups x 8 roles; group's 8 roles share an XCD (blockIdx%8).
// hbuf layout: ull[slot2][grp32][role8][row16][pair16]; word = {stamp32, bf16x2}
// ============================================================================
__global__ __launch_bounds__(512, 1) void lstm_stamp(
    const float* __restrict__ x,
    const float* __restrict__ h0, const float* __restrict__ c0,
    const float* __restrict__ z0,
    const float* __restrict__ W_ih, const float* __restrict__ W_hh,
    const float* __restrict__ b_ih, const float* __restrict__ b_hh,
    const float* __restrict__ Wfc, const float* __restrict__ bfc,
    ull* __restrict__ hbuf, float* __restrict__ out)
{
    __shared__ __align__(16) uint16_t w_sh[NKC * 8 * 64 * 8];  // 96 KB weights
    __shared__ __align__(16) uint16_t a_sh[NKC * 4 * 16 * 8];  // 12 KB A-frags
    __shared__ float g_sh[16 * GSTR];
    __shared__ float zp_sh[2][8][16];

    const int tid  = threadIdx.x;
    const int lane = tid & 63, wv = tid >> 6;
    // same-XCD remap: xcd = bid&7 identical for all 8 roles of a group
    const int bid  = blockIdx.x;
    const int mm   = bid >> 3;
    const int role = mm & 7, grp = (bid & 7) * 4 + (mm >> 3);
    const int b0   = grp * 16;
    const int arow = tid >> 5, auu = tid & 31;     // activation: 1 cell/thread
    const int u_g  = role * 32 + auu;
    const int xc   = (tid & 31) * 4;               // x-stage role
    const int grole = wv, grow = (tid >> 2) & 15, gwq = tid & 3;  // gather role

    // ---- one-time: swizzle this block's weight slice straight into LDS ----
    #pragma unroll
    for (int i = 0; i < 12; ++i) {
        int eo = i * 512 + tid;
        int lane2 = eo & 63, knt = eo >> 6;
        int nt = knt & 7;
        int k0 = (knt >> 3) * 32 + (lane2 >> 4) * 8;
        int lc = nt * 16 + (lane2 & 15);
        int col = (lc >> 5) * 256 + role * 32 + (lc & 31);
        const float* src = (k0 < II) ? &W_ih[(size_t)col * (II + 1) + k0]
                                     : &W_hh[(size_t)col * HH + (k0 - II)];
        ushort4 lo, hi;
        lo.x = f2bf(src[0]); lo.y = f2bf(src[1]); lo.z = f2bf(src[2]); lo.w = f2bf(src[3]);
        hi.x = f2bf(src[4]); hi.y = f2bf(src[5]); hi.z = f2bf(src[6]); hi.w = f2bf(src[7]);
        *(ushort4*)&w_sh[eo * 8 + 0] = lo;
        *(ushort4*)&w_sh[eo * 8 + 4] = hi;
    }

    // ---- per-thread loop invariants ----
    float bia[4], wzv[4];
    #pragma unroll
    for (int g = 0; g < 4; ++g) {
        int c = g * 256 + u_g;
        bia[g] = b_ih[c] + b_hh[c];
        wzv[g] = W_ih[(size_t)c * (II + 1) + II];   // z column (col 128)
    }
    float wfc8[8];
    #pragma unroll
    for (int j = 0; j < 8; ++j) wfc8[j] = Wfc[grole * 32 + gwq * 8 + j];
    const float bfcs = bfc[0];
    const float z0r  = z0[b0 + arow];
    float c_r = c0[(size_t)(b0 + arow) * HH + u_g];

    // ---- h0 -> a_sh (all roles), x0 -> a_sh ----
    {
        const float* hp = h0 + (size_t)(b0 + grow) * HH + grole * 32 + gwq * 8;
        uint4 pw;
        pw.x = (uint32_t)f2bf(hp[0]) | ((uint32_t)f2bf(hp[1]) << 16);
        pw.y = (uint32_t)f2bf(hp[2]) | ((uint32_t)f2bf(hp[3]) << 16);
        pw.z = (uint32_t)f2bf(hp[4]) | ((uint32_t)f2bf(hp[5]) << 16);
        pw.w = (uint32_t)f2bf(hp[6]) | ((uint32_t)f2bf(hp[7]) << 16);
        *(uint4*)&a_sh[(((4 + grole) * 4 + gwq) * 16 + grow) * 8] = pw;
    }
    {
        float4 xv = *(const float4*)&x[(size_t)(b0 + arow) * II + xc];
        int kcx = xc >> 5, gx = (xc >> 3) & 3, jx = xc & 7;
        ushort4 p;
        p.x = f2bf(xv.x); p.y = f2bf(xv.y); p.z = f2bf(xv.z); p.w = f2bf(xv.w);
        *(ushort4*)&a_sh[((kcx * 4 + gx) * 16 + arow) * 8 + jx] = p;
    }

    for (int t = 0; t <= TT; ++t) {
        // prefetch x_{t+1} (issued before the poll; consumed after barrier B)
        float4 xn = make_float4(0.f, 0.f, 0.f, 0.f);
        if (t + 1 < TT)
            xn = *(const float4*)&x[(size_t)(t + 1) * (BB * II) + (size_t)(b0 + arow) * II + xc];

        if (t > 0) {
            const int par = (t - 1) & 1;
            const ull* hb = (const ull*)hbuf
                + ((((size_t)par * 32 + grp) * 8 + grole) * 16 + grow) * 16 + gwq * 4;
            ull q0, q1, q2, q3;
            uint32_t it = 0;
            for (;;) {
                q0 = __hip_atomic_load(hb + 0, __ATOMIC_RELAXED, __HIP_MEMORY_SCOPE_AGENT);
                q1 = __hip_atomic_load(hb + 1, __ATOMIC_RELAXED, __HIP_MEMORY_SCOPE_AGENT);
                q2 = __hip_atomic_load(hb + 2, __ATOMIC_RELAXED, __HIP_MEMORY_SCOPE_AGENT);
                q3 = __hip_atomic_load(hb + 3, __ATOMIC_RELAXED, __HIP_MEMORY_SCOPE_AGENT);
                uint32_t s0 = (uint32_t)(q0 >> 32), s1 = (uint32_t)(q1 >> 32);
                uint32_t s2 = (uint32_t)(q2 >> 32), s3 = (uint32_t)(q3 >> 32);
                uint32_t smin = min(min(s0, s1), min(s2, s3));
                if (smin >= (uint32_t)t) break;
                __builtin_amdgcn_s_sleep(1);
                if (++it > (1u << 22)) break;  // hang-safety
            }
            uint32_t w0 = (uint32_t)q0, w1 = (uint32_t)q1;
            uint32_t w2 = (uint32_t)q2, w3 = (uint32_t)q3;
            uint4 pw; pw.x = w0; pw.y = w1; pw.z = w2; pw.w = w3;
            *(uint4*)&a_sh[(((4 + grole) * 4 + gwq) * 16 + grow) * 8] = pw;
            float p = bf2lo(w0) * wfc8[0] + bf2hi(w0) * wfc8[1]
                    + bf2lo(w1) * wfc8[2] + bf2hi(w1) * wfc8[3]
                    + bf2lo(w2) * wfc8[4] + bf2hi(w2) * wfc8[5]
                    + bf2lo(w3) * wfc8[6] + bf2hi(w3) * wfc8[7];
            p += __shfl_xor(p, 1, 64);
            p += __shfl_xor(p, 2, 64);
            if (gwq == 0) zp_sh[t & 1][grole][grow] = p;
        }
        __syncthreads();  // A: a_sh (x_t, h_{t-1}) + zp_sh ready

        if (t == TT) {    // epilogue: emit z_{TT-1} only
            if (role == 0 && tid < 16) {
                float s = bfcs;
                #pragma unroll
                for (int r = 0; r < 8; ++r) s += zp_sh[TT & 1][r][tid];
                out[(size_t)(TT - 1) * BB + b0 + tid] = ftanh(s);
            }
            break;
        }

        // ---- MFMA: gates[16][128] = A[16][384] * Wslice, wave = n-tile ----
        f32x4 acc0 = {0.f, 0.f, 0.f, 0.f}, acc1 = {0.f, 0.f, 0.f, 0.f};
        #pragma unroll
        for (int kc = 0; kc < NKC; kc += 2) {
            bf16x8 a0 = *(const bf16x8*)&a_sh[((kc * 4 + (lane >> 4)) * 16 + (lane & 15)) * 8];
            bf16x8 bv0 = *(const bf16x8*)&w_sh[((kc * 8 + wv) * 64 + lane) * 8];
            acc0 = __builtin_amdgcn_mfma_f32_16x16x32_bf16(a0, bv0, acc0, 0, 0, 0);
            bf16x8 a1 = *(const bf16x8*)&a_sh[(((kc + 1) * 4 + (lane >> 4)) * 16 + (lane & 15)) * 8];
            bf16x8 bv1 = *(const bf16x8*)&w_sh[(((kc + 1) * 8 + wv) * 64 + lane) * 8];
            acc1 = __builtin_amdgcn_mfma_f32_16x16x32_bf16(a1, bv1, acc1, 0, 0, 0);
        }
        f32x4 acc = acc0 + acc1;
        {
            int r0 = (lane >> 4) * 4, cb = wv * 16 + (lane & 15);
            #pragma unroll
            for (int i = 0; i < 4; ++i) g_sh[(r0 + i) * GSTR + cb] = acc[i];
        }
        __syncthreads();  // B: gates ready; all a_sh reads done

        // stage x_{t+1}
        {
            int kcx = xc >> 5, gx = (xc >> 3) & 3, jx = xc & 7;
            ushort4 p;
            p.x = f2bf(xn.x); p.y = f2bf(xn.y); p.z = f2bf(xn.z); p.w = f2bf(xn.w);
            *(ushort4*)&a_sh[((kcx * 4 + gx) * 16 + arow) * 8 + jx] = p;
        }

        // ---- activation: one cell per thread ----
        float zp_;
        if (t == 0) {
            zp_ = z0r;
        } else {
            float s = bfcs;
            #pragma unroll
            for (int r = 0; r < 8; ++r) s += zp_sh[t & 1][r][arow];
            zp_ = ftanh(s);
            if (role == 0 && auu == 0)
                out[(size_t)(t - 1) * BB + b0 + arow] = zp_;
        }
        float gi = g_sh[arow * GSTR +      auu] + bia[0] + wzv[0] * zp_;
        float gf = g_sh[arow * GSTR + 32 + auu] + bia[1] + wzv[1] * zp_;
        float gg = g_sh[arow * GSTR + 64 + auu] + bia[2] + wzv[2] * zp_;
        float go = g_sh[arow * GSTR + 96 + auu] + bia[3] + wzv[3] * zp_;
        float ig = fsig(gi), fg = fsig(gf), gc = ftanh(gg), og = fsig(go);
        float cn = fg * c_r + ig * gc;
        c_r = cn;
        float hn = og * ftanh(cn);

        // publish {h pair, stamp t+1} as one 8B relaxed atomic (IF-coherent)
        uint32_t hb16 = f2bf(hn);
        uint32_t nb = __shfl_down(hb16, 1, 64);
        if (!(auu & 1)) {
            ull q = ((ull)(uint32_t)(t + 1) << 32) | (ull)(hb16 | (nb << 16));
            __hip_atomic_store(
                hbuf + ((((size_t)(t & 1) * 32 + grp) * 8 + role) * 16 + arow) * 16 + (auu >> 1),
                q, __ATOMIC_RELAXED, __HIP_MEMORY_SCOPE_AGENT);
        }

        if (t == TT - 1) {
            size_t ho = (size_t)TT * BB + (size_t)(b0 + arow) * HH + u_g;
            out[ho] = hn;
            out[ho + (size_t)BB * HH] = cn;
        }
        // no barrier C: stamps make publishes self-synchronizing
    }
}

// ============================================================================
// FALLBACK (ws_size < 1 MB): proven R4 flag-based kernel, verbatim.
// ============================================================================
__global__ __launch_bounds__(512, 1) void lstm_flags(
    const float* __restrict__ x,
    const float* __restrict__ h0, const float* __restrict__ c0,
    const float* __restrict__ z0,
    const float* __restrict__ W_ih, const float* __restrict__ W_hh,
    const float* __restrict__ b_ih, const float* __restrict__ b_hh,
    const float* __restrict__ Wfc, const float* __restrict__ bfc,
    uint32_t* __restrict__ flags, uint32_t* __restrict__ hbuf,
    float* __restrict__ out)
{
    __shared__ __align__(16) uint16_t w_sh[NKC * 8 * 64 * 8];
    __shared__ __align__(16) uint16_t a_sh[NKC * 4 * 16 * 8];
    __shared__ float g_sh[16 * GSTR];
    __shared__ float zp_sh[8 * 16];

    const int tid  = threadIdx.x;
    const int lane = tid & 63, wv = tid >> 6;
    const int grp  = blockIdx.x >> 3, role = blockIdx.x & 7;
    const int b0   = grp * 16;
    const int arow = tid >> 5, auu = tid & 31;
    const int u_g  = role * 32 + auu;
    const int xc   = (tid & 31) * 4;
    const int grole = wv, grow = (tid >> 2) & 15, gwq = tid & 3;

    #pragma unroll
    for (int i = 0; i < 12; ++i) {
        int eo = i * 512 + tid;
        int lane2 = eo & 63, knt = eo >> 6;
        int nt = knt & 7;
        int k0 = (knt >> 3) * 32 + (lane2 >> 4) * 8;
        int lc = nt * 16 + (lane2 & 15);
        int col = (lc >> 5) * 256 + role * 32 + (lc & 31);
        const float* src = (k0 < II) ? &W_ih[(size_t)col * (II + 1) + k0]
                                     : &W_hh[(size_t)col * HH + (k0 - II)];
        ushort4 lo, hi;
        lo.x = f2bf(src[0]); lo.y = f2bf(src[1]); lo.z = f2bf(src[2]); lo.w = f2bf(src[3]);
        hi.x = f2bf(src[4]); hi.y = f2bf(src[5]); hi.z = f2bf(src[6]); hi.w = f2bf(src[7]);
        *(ushort4*)&w_sh[eo * 8 + 0] = lo;
        *(ushort4*)&w_sh[eo * 8 + 4] = hi;
    }

    float bia[4], wzv[4];
    #pragma unroll
    for (int g = 0; g < 4; ++g) {
        int c = g * 256 + u_g;
        bia[g] = b_ih[c] + b_hh[c];
        wzv[g] = W_ih[(size_t)c * (II + 1) + II];
    }
    float wfc8[8];
    #pragma unroll
    for (int j = 0; j < 8; ++j) wfc8[j] = Wfc[grole * 32 + gwq * 8 + j];
    const float bfcs = bfc[0];
    const float z0r  = z0[b0 + arow];
    float c_r = c0[(size_t)(b0 + arow) * HH + u_g];

    {
        const float* hp = h0 + (size_t)(b0 + grow) * HH + grole * 32 + gwq * 8;
        uint4 pw;
        pw.x = (uint32_t)f2bf(hp[0]) | ((uint32_t)f2bf(hp[1]) << 16);
        pw.y = (uint32_t)f2bf(hp[2]) | ((uint32_t)f2bf(hp[3]) << 16);
        pw.z = (uint32_t)f2bf(hp[4]) | ((uint32_t)f2bf(hp[5]) << 16);
        pw.w = (uint32_t)f2bf(hp[6]) | ((uint32_t)f2bf(hp[7]) << 16);
        *(uint4*)&a_sh[(((4 + grole) * 4 + gwq) * 16 + grow) * 8] = pw;
    }
    {
        float4 xv = *(const float4*)&x[(size_t)(b0 + arow) * II + xc];
        int kcx = xc >> 5, gx = (xc >> 3) & 3, jx = xc & 7;
        ushort4 p;
        p.x = f2bf(xv.x); p.y = f2bf(xv.y); p.z = f2bf(xv.z); p.w = f2bf(xv.w);
        *(ushort4*)&a_sh[((kcx * 4 + gx) * 16 + arow) * 8 + jx] = p;
    }

    for (int t = 0; t <= TT; ++t) {
        float4 xn = make_float4(0.f, 0.f, 0.f, 0.f);
        if (t + 1 < TT)
            xn = *(const float4*)&x[(size_t)(t + 1) * (BB * II) + (size_t)(b0 + arow) * II + xc];

        if (t > 0) {
            spin_ge(&flags[grp * 8 + grole], (uint32_t)t);
            const int par = (t - 1) & 1;
            uint32_t* hb = hbuf + (((size_t)par * 32 + grp) * 8 + grole) * 256
                         + grow * 16 + gwq * 4;
            uint32_t w0 = __hip_atomic_load(hb + 0, __ATOMIC_RELAXED, __HIP_MEMORY_SCOPE_AGENT);
            uint32_t w1 = __hip_atomic_load(hb + 1, __ATOMIC_RELAXED, __HIP_MEMORY_SCOPE_AGENT);
            uint32_t w2 = __hip_atomic_load(hb + 2, __ATOMIC_RELAXED, __HIP_MEMORY_SCOPE_AGENT);
            uint32_t w3 = __hip_atomic_load(hb + 3, __ATOMIC_RELAXED, __HIP_MEMORY_SCOPE_AGENT);
            uint4 pw; pw.x = w0; pw.y = w1; pw.z = w2; pw.w = w3;
            *(uint4*)&a_sh[(((4 + grole) * 4 + gwq) * 16 + grow) * 8] = pw;
            float p = bf2lo(w0) * wfc8[0] + bf2hi(w0) * wfc8[1]
                    + bf2lo(w1) * wfc8[2] + bf2hi(w1) * wfc8[3]
                    + bf2lo(w2) * wfc8[4] + bf2hi(w2) * wfc8[5]
                    + bf2lo(w3) * wfc8[6] + bf2hi(w3) * wfc8[7];
            p += __shfl_xor(p, 1, 64);
            p += __shfl_xor(p, 2, 64);
            if (gwq == 0) zp_sh[grole * 16 + grow] = p;
        }
        __syncthreads();

        if (t == TT) {
            if (role == 0 && tid < 16) {
                float s = bfcs;
                #pragma unroll
                for (int r = 0; r < 8; ++r) s += zp_sh[r * 16 + tid];
                out[(size_t)(TT - 1) * BB + b0 + tid] = ftanh(s);
            }
            break;
        }

        f32x4 acc0 = {0.f, 0.f, 0.f, 0.f}, acc1 = {0.f, 0.f, 0.f, 0.f};
        #pragma unroll
        for (int kc = 0; kc < NKC; kc += 2) {
            bf16x8 a0 = *(const bf16x8*)&a_sh[((kc * 4 + (lane >> 4)) * 16 + (lane & 15)) * 8];
            bf16x8 bv0 = *(const bf16x8*)&w_sh[((kc * 8 + wv) * 64 + lane) * 8];
            acc0 = __builtin_amdgcn_mfma_f32_16x16x32_bf16(a0, bv0, acc0, 0, 0, 0);
            bf16x8 a1 = *(const bf16x8*)&a_sh[(((kc + 1) * 4 + (lane >> 4)) * 16 + (lane & 15)) * 8];
            bf16x8 bv1 = *(const bf16x8*)&w_sh[(((kc + 1) * 8 + wv) * 64 + lane) * 8];
            acc1 = __builtin_amdgcn_mfma_f32_16x16x32_bf16(a1, bv1, acc1, 0, 0, 0);
        }
        f32x4 acc = acc0 + acc1;
        {
            int r0 = (lane >> 4) * 4, cb = wv * 16 + (lane & 15);
            #pragma unroll
            for (int i = 0; i < 4; ++i) g_sh[(r0 + i) * GSTR + cb] = acc[i];
        }
        __syncthreads();

        {
            int kcx = xc >> 5, gx = (xc >> 3) & 3, jx = xc & 7;
            ushort4 p;
            p.x = f2bf(xn.x); p.y = f2bf(xn.y); p.z = f2bf(xn.z); p.w = f2bf(xn.w);
            *(ushort4*)&a_sh[((kcx * 4 + gx) * 16 + arow) * 8 + jx] = p;
        }

        float zp_;
        if (t == 0) {
            zp_ = z0r;
        } else {
            float s = bfcs;
            #pragma unroll
            for (int r = 0; r < 8; ++r) s += zp_sh[r * 16 + arow];
            zp_ = ftanh(s);
            if (role == 0 && auu == 0)
                out[(size_t)(t - 1) * BB + b0 + arow] = zp_;
        }
        float gi = g_sh[arow * GSTR +      auu] + bia[0] + wzv[0] * zp_;
        float gf = g_sh[arow * GSTR + 32 + auu] + bia[1] + wzv[1] * zp_;
        float gg = g_sh[arow * GSTR + 64 + auu] + bia[2] + wzv[2] * zp_;
        float go = g_sh[arow * GSTR + 96 + auu] + bia[3] + wzv[3] * zp_;
        float ig = fsig(gi), fg = fsig(gf), gc = ftanh(gg), og = fsig(go);
        float cn = fg * c_r + ig * gc;
        c_r = cn;
        float hn = og * ftanh(cn);

        uint32_t hb16 = f2bf(hn);
        uint32_t nb = __shfl_down(hb16, 1, 64);
        if (!(auu & 1)) {
            __hip_atomic_store(
                hbuf + (((size_t)(t & 1) * 32 + grp) * 8 + role) * 256 + arow * 16 + (auu >> 1),
                hb16 | (nb << 16), __ATOMIC_RELAXED, __HIP_MEMORY_SCOPE_AGENT);
        }

        if (t == TT - 1) {
            size_t ho = (size_t)TT * BB + (size_t)(b0 + arow) * HH + u_g;
            out[ho] = hn;
            out[ho + (size_t)BB * HH] = cn;
        }
        __syncthreads();
        if (tid == 0)
            __hip_atomic_store(&flags[grp * 8 + role], (uint32_t)(t + 1),
                               __ATOMIC_RELEASE, __HIP_MEMORY_SCOPE_AGENT);
    }
}

extern "C" void kernel_launch(void* const* d_in, const int* in_sizes, int n_in,
                              void* d_out, int out_size, void* d_ws, size_t ws_size,
                              hipStream_t stream) {
    const float* x    = (const float*)d_in[0];
    const float* h0   = (const float*)d_in[1];
    const float* c0   = (const float*)d_in[2];
    const float* z0   = (const float*)d_in[3];
    const float* W_ih = (const float*)d_in[4];
    const float* W_hh = (const float*)d_in[5];
    const float* b_ih = (const float*)d_in[6];
    const float* b_hh = (const float*)d_in[7];
    const float* Wfc  = (const float*)d_in[8];
    const float* bfc  = (const float*)d_in[9];
    float* out = (float*)d_out;

    const size_t HBUF_BYTES = (size_t)2 * 32 * 8 * 16 * 16 * 8;  // 1 MB
    if (ws_size >= HBUF_BYTES) {
        ull* hbuf = (ull*)d_ws;
        hipMemsetAsync(d_ws, 0, HBUF_BYTES, stream);  // zero stamps (replay-safe)
        lstm_stamp<<<256, 512, 0, stream>>>(x, h0, c0, z0, W_ih, W_hh, b_ih, b_hh,
                                            Wfc, bfc, hbuf, out);
    } else {
        uint32_t* flags = (uint32_t*)d_ws;
        uint32_t* hbuf  = (uint32_t*)((char*)d_ws + 4096);
        zero_flags<<<1, 256, 0, stream>>>(flags);
        lstm_flags<<<256, 512, 0, stream>>>(x, h0, c0, z0, W_ih, W_hh, b_ih, b_hh,
                                            Wfc, bfc, flags, hbuf, out);
    }
}